// Round 8
// baseline (79.087 us; speedup 1.0000x reference)
//
#include <hip/hip_runtime.h>
#include <math.h>

// B=8, N=2048, coords [B,N,3] f32. LDDT loss, upper-triangle formulation:
// both distance matrices are symmetric so num/den over {j>i} equals the
// full-matrix ratio; j>i excludes the diagonal, making the reference's
// true_d > 1e-8 test vacuous for this data.
//
// R8: the inner loop has been LDS-pipe-bound in every prior round
// (ds_read_b128 ~12 cy on the per-CU LDS pipe shared by 4 SIMDs; 2/iter x 4
// waves = 96 LDS-cy vs ~50 SIMD-cy VALU -> 24 CU-cy/wave-iter = the observed
// 11.5 us). Fix: NO LDS AT ALL. Each wave keeps the 64-point j-tile in its
// own lanes (lane l <-> point j0+l, coalesced load once); the loop
// broadcasts lane j's coords with v_readlane_b32 (VALU pipe, SGPR dest).
// Scoring stays on ballots (SALU bincount, fits under the VALU window).
// No __syncthreads anywhere; per-wave direct partial stores.
constexpr int B  = 8;
constexpr int N  = 2048;
constexpr int TI = 256;        // threads per block (4 independent waves)
constexpr int TJ = 64;         // j-points per tile == wave width
constexpr int TILES = 144;     // per batch: c in [4a, 32), a in [0,8)
constexpr int WPB = TI / 64;   // waves per block
constexpr int SLOTS = TILES * WPB;   // 576 per batch

__device__ __forceinline__ float bcast(float v, int j)
{
    // wave-uniform lane index -> v_readlane_b32 (VALU pipe, no LDS)
    return __int_as_float(__builtin_amdgcn_readlane(__float_as_int(v), j));
}

template <bool CHECK>
__device__ __forceinline__ void inner_loop(
    float Pjx, float Pjy, float Pjz,   // this lane's j-point (pred)
    float Tjx, float Tjy, float Tjz,   // this lane's j-point (true)
    float pix, float piy, float piz,
    float tix, float tiy, float tiz,
    int k0, int lane,                  // CHECK tiles: lane < k0+j <=> j0+j > i
    unsigned& c0, unsigned& c1, unsigned& c2, unsigned& c3, unsigned& cd)
{
    #pragma unroll 8
    for (int j = 0; j < TJ; ++j) {
        float pjx = bcast(Pjx, j), pjy = bcast(Pjy, j), pjz = bcast(Pjz, j);
        float tjx = bcast(Tjx, j), tjy = bcast(Tjy, j), tjz = bcast(Tjz, j);

        float dx = pix - pjx, dy = piy - pjy, dz = piz - pjz;
        float pd2 = fmaf(dx, dx, fmaf(dy, dy, dz * dz));
        float ex = tix - tjx, ey = tiy - tjy, ez = tiz - tjz;
        float td2 = fmaf(ex, ex, fmaf(ey, ey, ez * ez));

        bool keep = td2 < 225.0f;            // local mask (squared domain)
        if (CHECK) keep = keep && (lane < k0 + j);

        float diff = fabsf(__builtin_amdgcn_sqrtf(pd2) - __builtin_amdgcn_sqrtf(td2));
        // gate once on VALU so the 4 bin ballots need no SALU mask-AND
        float dg = keep ? diff : 1e9f;

        cd += __popcll(__ballot(keep));
        // cumulative bins: score = .5*[d<.5]+.25*[d<1]+.125*[d<2]+.125*[d<4]
        c0 += __popcll(__ballot(dg < 0.5f));
        c1 += __popcll(__ballot(dg < 1.0f));
        c2 += __popcll(__ballot(dg < 2.0f));
        c3 += __popcll(__ballot(dg < 4.0f));
    }
}

__global__ __launch_bounds__(TI) void lddt_partial(
    const float* __restrict__ pred,   // [B,N,3]
    const float* __restrict__ truec,  // [B,N,3]
    float2* __restrict__ part)        // [B, SLOTS]
{
    const int b = blockIdx.y;
    // decode linear tile index -> (a = i-tile, c = j-tile), c in [4a, 32)
    int r = blockIdx.x, a = 0;
    while (r >= 32 - 4 * a) { r -= 32 - 4 * a; ++a; }
    const int c = 4 * a + r;
    const int i0 = a * TI;
    const int j0 = c * TJ;
    const int t = threadIdx.x;
    const int wave = t >> 6;
    const int lane = t & 63;

    // this lane's i-point
    const int i = i0 + t;
    const float* pi = pred  + ((size_t)b * N + i) * 3;
    const float* ti = truec + ((size_t)b * N + i) * 3;
    const float pix = pi[0], piy = pi[1], piz = pi[2];
    const float tix = ti[0], tiy = ti[1], tiz = ti[2];

    // this lane's j-point (lane l of every wave holds point j0+l)
    const float* pj = pred  + ((size_t)b * N + j0 + lane) * 3;
    const float* tj = truec + ((size_t)b * N + j0 + lane) * 3;
    const float Pjx = pj[0], Pjy = pj[1], Pjz = pj[2];
    const float Tjx = tj[0], Tjy = tj[1], Tjz = tj[2];

    unsigned c0 = 0, c1 = 0, c2 = 0, c3 = 0, cd = 0;

    if (c >= 4 * a + 4) {   // off-diagonal tile: all j > i guaranteed
        inner_loop<false>(Pjx, Pjy, Pjz, Tjx, Tjy, Tjz,
                          pix, piy, piz, tix, tiy, tiz,
                          0, lane, c0, c1, c2, c3, cd);
    } else {                // diagonal-band tile: per-lane j>i compare
        const int k0 = j0 - (i0 + 64 * wave);
        inner_loop<true>(Pjx, Pjy, Pjz, Tjx, Tjy, Tjz,
                         pix, piy, piz, tix, tiy, tiz,
                         k0, lane, c0, c1, c2, c3, cd);
    }

    // ballot counters are wave-uniform: lane 0 of each wave stores its slot
    if (lane == 0) {
        float n = 0.5f * (float)c0 + 0.25f * (float)c1
                + 0.125f * (float)c2 + 0.125f * (float)c3;
        part[(size_t)b * SLOTS + blockIdx.x * WPB + wave] =
            make_float2(n, (float)cd);
    }
}

// 512 threads = 8 waves; wave w reduces batch w's SLOTS slots.
__global__ __launch_bounds__(512) void lddt_reduce(
    const float2* __restrict__ part,  // [B, SLOTS]
    float* __restrict__ out)          // [1]
{
    const int t = threadIdx.x;
    const int w = t >> 6;     // batch
    const int l = t & 63;

    float n = 0.0f, d = 0.0f;
    for (int s = l; s < SLOTS; s += 64) {
        float2 v = part[(size_t)w * SLOTS + s];
        n += v.x;
        d += v.y;
    }
    for (int off = 32; off > 0; off >>= 1) {
        n += __shfl_down(n, off, 64);
        d += __shfl_down(d, off, 64);
    }

    __shared__ float acc[B];
    if (l == 0) acc[w] = 1.0f - n / fmaxf(d, 1e-8f);
    __syncthreads();

    if (t == 0) {
        float s = 0.0f;
        #pragma unroll
        for (int b = 0; b < B; ++b) s += acc[b];
        out[0] = s / (float)B;
    }
}

extern "C" void kernel_launch(void* const* d_in, const int* in_sizes, int n_in,
                              void* d_out, int out_size, void* d_ws, size_t ws_size,
                              hipStream_t stream)
{
    const float* pred  = (const float*)d_in[0];
    const float* truec = (const float*)d_in[1];
    float* out   = (float*)d_out;
    float2* part = (float2*)d_ws;   // B * SLOTS float2 = 36 KB

    dim3 grid(TILES, B);
    lddt_partial<<<grid, TI, 0, stream>>>(pred, truec, part);
    lddt_reduce<<<1, 512, 0, stream>>>(part, out);
}